// Round 10
// baseline (95.091 us; speedup 1.0000x reference)
//
#include <hip/hip_runtime.h>
#include <hip/hip_bf16.h>

// Flash attention fwd, causal + key-padding, B=4 S=4096 D=64, fp32 in/out.
// Round 10: round-5/9 green base, occupancy-focused:
//  (a) K/V converted to bf16 at LOAD time (prefetch regs halved: -16 VGPR),
//  (b) biassh/padpre deleted; block-wide anyPad flag in prologue, rare-path
//      global pad reads (same byte->lane map as the old bias),
//  (c) __launch_bounds__(256,4): target 4 waves/SIMD (was reg-capped at 3),
//  (d) merge kernel at 512 blocks (was 128: 0.5 block/CU, ~10us),
//  (e) always-rescale softmax (round-5 exact), T5 setprio on MFMA clusters.

#define S_LEN 4096
#define D_DIM 64
#define NBATCH 4
#define QBLK 128
#define KVBLK 64
#define NQB (S_LEN / QBLK)                // 32 q-blocks per batch
#define SLOT_F (QBLK * D_DIM + 2 * QBLK)  // 8448 floats per partial slot

typedef __attribute__((ext_vector_type(16))) float f32x16;
typedef __attribute__((ext_vector_type(4))) float f32x4;
typedef __attribute__((ext_vector_type(8))) short s16x8;
typedef __attribute__((ext_vector_type(4))) short s16x4;
typedef __attribute__((ext_vector_type(2))) unsigned int u32x2;

#define FK(n) ((((n) ^ ((n) >> 3)) & 7) << 4)                    // K swizzle
#define FV(d) (((((d) & 7) << 4)) ^ ((((d) >> 3) & 1) << 3))     // V^T swizzle

__device__ __forceinline__ unsigned short f2bfu(float f) {
  return __builtin_bit_cast(unsigned short, __float2bfloat16(f));
}
__device__ __forceinline__ unsigned pk2(float a, float b) {
  return (unsigned)f2bfu(a) | ((unsigned)f2bfu(b) << 16);
}

__global__ __launch_bounds__(256, 4) void fattn_partial(
    const float* __restrict__ Qg, const float* __restrict__ Kg,
    const float* __restrict__ Vg, const unsigned char* __restrict__ Pad,
    float* __restrict__ Og, float* __restrict__ Ws, int nchunk)
{
  // Heavy-first dispatch: rank 0 = largest q-block index.
  const int wid = blockIdx.x;
  const int r   = wid / nchunk;
  const int ci  = wid % nchunk;
  const int Qb  = (NQB - 1) - (r >> 2);
  const int b   = r & 3;
  const int qbi = b * NQB + Qb;
  const int q0  = Qb * QBLK;

  const int ntt = 2 * Qb + 2;                    // causal: KV tiles needed
  const int cw  = (ntt + nchunk - 1) / nchunk;
  const int t0  = ci * cw;
  const int t1  = (t0 + cw < ntt) ? (t0 + cw) : ntt;
  if (t0 >= t1) return;

  const int tid = threadIdx.x;
  const int w   = tid >> 6;          // wave 0..3 -> q rows [q0+32w, q0+32w+32)
  const int l   = tid & 63;
  const int ql  = l & 31;            // q within wave tile
  const int hi  = l >> 5;
  const int qw0 = q0 + 32 * w;
  const int qa  = qw0 + ql;          // absolute q row for this lane

  // staging roles (cover 64 rows x 16 float4 with 256 threads)
  const int sq  = l & 3;
  const int sm  = (l >> 2) & 3;
  const int sc2 = l >> 4;
  const int snb = 4 * w + 16 * sc2;  // n-chunk base (multiple of 4)

  __shared__ short Ksh[2][KVBLK * D_DIM];   // [n][d] bf16, FK-swizzled
  __shared__ short Vtsh[2][D_DIM * KVBLK];  // [d][n] bf16 (V^T), FV-swizzled
  __shared__ int anyPadSh;

  const unsigned char* PadB = Pad + (size_t)b * S_LEN;

  // ---- prologue: block-wide padding flag for this chunk's key range ----
  if (tid == 0) anyPadSh = 0;
  __syncthreads();
  {
    const int nk  = (t1 - t0) * KVBLK;      // <= 512
    const int idx = 2 * tid;
    if (idx < nk) {
      const unsigned char* pp = PadB + t0 * KVBLK + idx;
      const bool nz = pp[0] || ((idx + 1 < nk) ? pp[1] : (unsigned char)0);
      if (nz) anyPadSh = 1;                 // benign same-value race
    }
  }

  // ---- Q fragments (B-operand), pre-scaled by 1/8 ----
  s16x8 qf[4];
  {
    const float* qp = Qg + ((size_t)(b * S_LEN + qa)) * D_DIM + 8 * hi;
    #pragma unroll
    for (int dc = 0; dc < 4; ++dc)
      #pragma unroll
      for (int j = 0; j < 8; ++j)
        qf[dc][j] = (short)f2bfu(qp[16 * dc + j] * 0.125f);
  }

  f32x16 acc[2];
  #pragma unroll
  for (int dt = 0; dt < 2; ++dt)
    #pragma unroll
    for (int i = 0; i < 16; ++i) acc[dt][i] = 0.f;
  float mrow = -INFINITY;
  float lrow = 0.f;

  u32x2 kpb[4], vpb[4];   // bf16-packed prefetch (converted at load)

#define LOAD_K(T) do {                                                       \
    const int kv0_ = (T) * KVBLK;                                            \
    _Pragma("unroll")                                                        \
    for (int s_ = 0; s_ < 4; ++s_) {                                         \
      const size_t go_ =                                                     \
          ((size_t)(b * S_LEN + kv0_ + snb + sq)) * D_DIM + 16 * s_ + 4 * sm;\
      const float4 kx = *(const float4*)(Kg + go_);                          \
      kpb[s_][0] = pk2(kx.x, kx.y); kpb[s_][1] = pk2(kx.z, kx.w);            \
    }                                                                        \
  } while (0)

#define LOAD_V(T) do {                                                       \
    const int kv0_ = (T) * KVBLK;                                            \
    _Pragma("unroll")                                                        \
    for (int s_ = 0; s_ < 4; ++s_) {                                         \
      const size_t go_ =                                                     \
          ((size_t)(b * S_LEN + kv0_ + snb + sq)) * D_DIM + 16 * s_ + 4 * sm;\
      const float4 vx = *(const float4*)(Vg + go_);                          \
      vpb[s_][0] = pk2(vx.x, vx.y); vpb[s_][1] = pk2(vx.z, vx.w);            \
    }                                                                        \
  } while (0)

#define STAGE(BUF) do {                                                      \
    _Pragma("unroll")                                                        \
    for (int s_ = 0; s_ < 4; ++s_) {                                         \
      const int d0_ = 16 * s_ + 4 * sm; const int nk_ = snb + sq;            \
      *(u32x2*)((char*)&Ksh[BUF][0] + nk_ * 128 + ((2 * d0_) ^ FK(nk_))) =   \
          kpb[s_];                                                           \
      unsigned u0 = vpb[s_][0], u1 = vpb[s_][1];                             \
      unsigned x_ = (sq & 2) ? u0 : u1;                                      \
      unsigned y_ = __shfl_xor(x_, 2);                                       \
      unsigned A0 = (sq & 2) ? y_ : u0;                                      \
      unsigned A1 = (sq & 2) ? u1 : y_;                                      \
      unsigned z0 = __shfl_xor(A0, 1);                                       \
      unsigned z1 = __shfl_xor(A1, 1);                                       \
      unsigned o0, o1;                                                       \
      if (sq & 1) { o0 = (z0 >> 16) | (A0 & 0xFFFF0000u);                    \
                    o1 = (z1 >> 16) | (A1 & 0xFFFF0000u); }                  \
      else        { o0 = (A0 & 0xFFFFu) | (z0 << 16);                        \
                    o1 = (A1 & 0xFFFFu) | (z1 << 16); }                      \
      const int dv_ = d0_ + sq;                                              \
      u32x2 vv2; vv2[0] = o0; vv2[1] = o1;                                   \
      *(u32x2*)((char*)&Vtsh[BUF][0] + dv_ * 128 + ((2 * snb) ^ FV(dv_))) = vv2;\
    }                                                                        \
  } while (0)

  LOAD_K(t0);
  LOAD_V(t0);
  STAGE(0);
  __syncthreads();
  const bool hasPad = (anyPadSh != 0);
  int cb = 0;

  for (int t = t0; t < t1; ++t) {
    const int kv0 = t * KVBLK;
    const bool more = (t + 1 < t1);
    if (more) LOAD_K(t + 1);

    // ---- S^T = mfma(A=K, B=Q): col=lane&31=q, row=k ----
    f32x16 sv[2];
    __builtin_amdgcn_s_setprio(1);
    #pragma unroll
    for (int kt = 0; kt < 2; ++kt) {
      f32x16 a;
      #pragma unroll
      for (int i = 0; i < 16; ++i) a[i] = 0.f;
      #pragma unroll
      for (int dc = 0; dc < 4; ++dc) {
        const int nr = 32 * kt + ql;
        const s16x8 kf = *(const s16x8*)((char*)&Ksh[cb][0] + nr * 128 +
                                         ((32 * dc + 16 * hi) ^ FK(nr)));
        a = __builtin_amdgcn_mfma_f32_32x32x16_bf16(kf, qf[dc], a, 0, 0, 0);
      }
      sv[kt] = a;
    }
    __builtin_amdgcn_s_setprio(0);

    if (more) LOAD_V(t + 1);

    // ---- padding (rare path) ----
    if (hasPad) {
      #pragma unroll
      for (int kt = 0; kt < 2; ++kt)
        #pragma unroll
        for (int r1 = 0; r1 < 4; ++r1) {
          const unsigned pd =
              *(const unsigned*)(PadB + kv0 + 32 * kt + 8 * r1 + 4 * hi);
          #pragma unroll
          for (int r0 = 0; r0 < 4; ++r0)
            if ((pd >> (8 * r0)) & 0xFFu) sv[kt][4 * r1 + r0] = -1e30f;
        }
    }
    // ---- causal mask (diagonal band only): k = kv0+32kt+8r1+4hi+r0 ----
    #pragma unroll
    for (int kt = 0; kt < 2; ++kt) {
      const int kvt = kv0 + 32 * kt;
      if (kvt + 31 > qw0) {
        #pragma unroll
        for (int r1 = 0; r1 < 4; ++r1)
          #pragma unroll
          for (int r0 = 0; r0 < 4; ++r0)
            if (kvt + 8 * r1 + 4 * hi + r0 > qa) sv[kt][4 * r1 + r0] = -1e30f;
      }
    }

    // ---- in-register online softmax (e-domain, always rescale) ----
    float vm = sv[0][0];
    #pragma unroll
    for (int kt = 0; kt < 2; ++kt)
      #pragma unroll
      for (int i = 0; i < 16; ++i) vm = fmaxf(vm, sv[kt][i]);
    vm = fmaxf(vm, __shfl_xor(vm, 32));           // merge across hi halves
    const float mn   = fmaxf(mrow, vm);
    const float corr = __expf(mrow - mn);
    mrow = mn;
    lrow *= corr;
    #pragma unroll
    for (int dt = 0; dt < 2; ++dt)
      #pragma unroll
      for (int i = 0; i < 16; ++i) acc[dt][i] *= corr;

    float rs = 0.f;
    #pragma unroll
    for (int kt = 0; kt < 2; ++kt)
      #pragma unroll
      for (int i = 0; i < 16; ++i) {
        const float p = __expf(sv[kt][i] - mn);
        sv[kt][i] = p;
        rs += p;
      }
    lrow += rs;                                   // own half-sum only

    // ---- O^T += mfma(A=V^T, B=P) ----
    // P B-frag in C/D-native k-order: elem j <-> k = 4hi+(j&3)+8*(j>>2).
    // V^T A-frag reads the SAME element->k map (two 8B LDS reads).
    __builtin_amdgcn_s_setprio(1);
    #pragma unroll
    for (int sk = 0; sk < 4; ++sk) {
      const int kt = sk >> 1, rb = 8 * (sk & 1);
      union { unsigned u[4]; s16x8 v; } pb;
      pb.u[0] = pk2(sv[kt][rb + 0], sv[kt][rb + 1]);
      pb.u[1] = pk2(sv[kt][rb + 2], sv[kt][rb + 3]);
      pb.u[2] = pk2(sv[kt][rb + 4], sv[kt][rb + 5]);
      pb.u[3] = pk2(sv[kt][rb + 6], sv[kt][rb + 7]);
      #pragma unroll
      for (int dt = 0; dt < 2; ++dt) {
        const int dr = 32 * dt + ql;
        const char* vrow = (char*)&Vtsh[cb][0] + dr * 128;
        const s16x4 v0 = *(const s16x4*)(vrow + ((32 * sk + 8 * hi) ^ FV(dr)));
        const s16x4 v1 = *(const s16x4*)(vrow + ((32 * sk + 16 + 8 * hi) ^ FV(dr)));
        s16x8 vf;
        vf[0] = v0[0]; vf[1] = v0[1]; vf[2] = v0[2]; vf[3] = v0[3];
        vf[4] = v1[0]; vf[5] = v1[1]; vf[6] = v1[2]; vf[7] = v1[3];
        acc[dt] = __builtin_amdgcn_mfma_f32_32x32x16_bf16(vf, pb.v, acc[dt], 0, 0, 0);
      }
    }
    __builtin_amdgcn_s_setprio(0);

    if (more) STAGE(cb ^ 1);
    __syncthreads();
    cb ^= 1;
  }

  // ---- epilogue: merge l across hi halves; write O^T-layout rows ----
  const float lt = lrow + __shfl_xor(lrow, 32);

  if (nchunk == 1) {
    const float inv = 1.0f / lt;
    #pragma unroll
    for (int dt = 0; dt < 2; ++dt)
      #pragma unroll
      for (int r1 = 0; r1 < 4; ++r1) {
        f32x4 o;
        #pragma unroll
        for (int r0 = 0; r0 < 4; ++r0) o[r0] = acc[dt][4 * r1 + r0] * inv;
        *(f32x4*)(Og + ((size_t)(b * S_LEN + qa)) * D_DIM +
                  32 * dt + 8 * r1 + 4 * hi) = o;
      }
  } else {
    float* slot = Ws + (size_t)(qbi * nchunk + ci) * SLOT_F;
    const int row = 32 * w + ql;
    #pragma unroll
    for (int dt = 0; dt < 2; ++dt)
      #pragma unroll
      for (int r1 = 0; r1 < 4; ++r1) {
        f32x4 o;
        #pragma unroll
        for (int r0 = 0; r0 < 4; ++r0) o[r0] = acc[dt][4 * r1 + r0];
        *(f32x4*)(slot + row * 64 + 32 * dt + 8 * r1 + 4 * hi) = o;
      }
    if (hi == 0) {
      slot[QBLK * D_DIM + row]        = mrow;
      slot[QBLK * D_DIM + QBLK + row] = lt;
    }
  }
}

__global__ __launch_bounds__(256, 8) void fattn_merge(
    const float* __restrict__ Ws, float* __restrict__ Og, int nchunk)
{
  const int blk = blockIdx.x;            // 512 = 128 qb * 4 quarters
  const int qbi = blk >> 2;
  const int qr  = blk & 3;
  const int Qb  = qbi & (NQB - 1);
  const int b   = qbi >> 5;
  const int tid = threadIdx.x;
  const int row = 32 * qr + (tid >> 3);  // q row within 128-block
  const int d0  = (tid & 7) * 8;         // 8 d-elems per thread

  const int ntt = 2 * Qb + 2;
  const int cw  = (ntt + nchunk - 1) / nchunk;
  const int nvalid = (ntt + cw - 1) / cw;

  const float* base = Ws + (size_t)qbi * nchunk * SLOT_F;

  float mstar = -INFINITY;
  for (int ci = 0; ci < nvalid; ++ci)
    mstar = fmaxf(mstar, base[(size_t)ci * SLOT_F + QBLK * D_DIM + row]);

  float lsum = 0.f;
  float o[8];
  #pragma unroll
  for (int k = 0; k < 8; ++k) o[k] = 0.f;

  for (int ci = 0; ci < nvalid; ++ci) {
    const float* slot = base + (size_t)ci * SLOT_F;
    const float wgt = __expf(slot[QBLK * D_DIM + row] - mstar);
    lsum += wgt * slot[QBLK * D_DIM + QBLK + row];
    const float4 ov0 = *(const float4*)(slot + row * 64 + d0);
    const float4 ov1 = *(const float4*)(slot + row * 64 + d0 + 4);
    o[0] += wgt * ov0.x; o[1] += wgt * ov0.y;
    o[2] += wgt * ov0.z; o[3] += wgt * ov0.w;
    o[4] += wgt * ov1.x; o[5] += wgt * ov1.y;
    o[6] += wgt * ov1.z; o[7] += wgt * ov1.w;
  }

  const float inv = 1.0f / lsum;
  float* op = Og + ((size_t)(b * S_LEN + Qb * QBLK + row)) * D_DIM + d0;
  f32x4 o0, o1;
  #pragma unroll
  for (int k = 0; k < 4; ++k) { o0[k] = o[k] * inv; o1[k] = o[4 + k] * inv; }
  *(f32x4*)(op) = o0;
  *(f32x4*)(op + 4) = o1;
}

extern "C" void kernel_launch(void* const* d_in, const int* in_sizes, int n_in,
                              void* d_out, int out_size, void* d_ws, size_t ws_size,
                              hipStream_t stream) {
  const float* Q = (const float*)d_in[0];
  const float* K = (const float*)d_in[1];
  const float* V = (const float*)d_in[2];
  const unsigned char* P = (const unsigned char*)d_in[3];
  float* O  = (float*)d_out;
  float* Ws = (float*)d_ws;

  const size_t slot_bytes = (size_t)SLOT_F * 4;
  const size_t nqb_total  = (size_t)NBATCH * NQB;   // 128
  int nchunk = 1;
  if      (ws_size >= nqb_total * 8 * slot_bytes) nchunk = 8;
  else if (ws_size >= nqb_total * 4 * slot_bytes) nchunk = 4;
  else if (ws_size >= nqb_total * 2 * slot_bytes) nchunk = 2;

  dim3 grid(NBATCH * NQB * nchunk);
  dim3 block(256);
  hipLaunchKernelGGL(fattn_partial, grid, block, 0, stream, Q, K, V, P, O, Ws, nchunk);
  if (nchunk > 1) {
    dim3 mgrid(NBATCH * NQB * 4);
    hipLaunchKernelGGL(fattn_merge, mgrid, dim3(256), 0, stream, Ws, O, nchunk);
  }
}

// Round 11
// 60.376 us; speedup vs baseline: 1.5750x; 1.5750x over previous
//
#include <hip/hip_runtime.h>
#include <hip/hip_bf16.h>

// Flash attention fwd, causal + key-padding, B=4 S=4096 D=64, fp32 in/out.
// Round 11: round-9 green math + round-10 keepers (bf16-at-load staging,
// anyPad prologue, 512-block merge, always-rescale), launch_bounds back to
// (256,3) (the (256,4) bound forced VGPR 84->64 and spilled: WRITE_SIZE
// 50->70MB, dur 95us). NEW: uniform work partition — every partial block
// processes exactly CL tiles (CL=4 or 8 by ws size), heavy-q first, so all
// blocks drain together (round 9's fixed nchunk gave 1-8 tile chunks and
// 22% time-avg occupancy). All blocks write slots; merge matches.

#define S_LEN 4096
#define D_DIM 64
#define NBATCH 4
#define QBLK 128
#define KVBLK 64
#define NQB (S_LEN / QBLK)                // 32 q-blocks per batch
#define SLOT_F (QBLK * D_DIM + 2 * QBLK)  // 8448 floats per partial slot

typedef __attribute__((ext_vector_type(16))) float f32x16;
typedef __attribute__((ext_vector_type(4))) float f32x4;
typedef __attribute__((ext_vector_type(8))) short s16x8;
typedef __attribute__((ext_vector_type(4))) short s16x4;
typedef __attribute__((ext_vector_type(2))) unsigned int u32x2;

#define FK(n) ((((n) ^ ((n) >> 3)) & 7) << 4)                    // K swizzle
#define FV(d) (((((d) & 7) << 4)) ^ ((((d) >> 3) & 1) << 3))     // V^T swizzle

__device__ __forceinline__ unsigned short f2bfu(float f) {
  return __builtin_bit_cast(unsigned short, __float2bfloat16(f));
}
__device__ __forceinline__ unsigned pk2(float a, float b) {
  return (unsigned)f2bfu(a) | ((unsigned)f2bfu(b) << 16);
}

__global__ __launch_bounds__(256, 3) void fattn_partial(
    const float* __restrict__ Qg, const float* __restrict__ Kg,
    const float* __restrict__ Vg, const unsigned char* __restrict__ Pad,
    float* __restrict__ Ws, int CL, int TOTC)
{
  // Uniform partition: enumeration index u -> (Qb, ci) with
  // nch(q) = ceil((2q+2)/CL) chunks per q-block. Heavy-first dispatch.
  const int wid = blockIdx.x;
  const int b   = wid & 3;
  const int u   = TOTC - 1 - (wid >> 2);
  int Qb = 0, ci = 0;
  {
    int uu = u, q = 0;
    while (true) {
      const int nch = (2 * q + 2 + CL - 1) / CL;
      if (uu < nch) { ci = uu; break; }
      uu -= nch; ++q;
    }
    Qb = q;
  }
  const int q0  = Qb * QBLK;
  const int ntt = 2 * Qb + 2;
  const int t0  = ci * CL;
  const int t1  = (t0 + CL < ntt) ? (t0 + CL) : ntt;

  const int tid = threadIdx.x;
  const int w   = tid >> 6;          // wave 0..3 -> q rows [q0+32w, q0+32w+32)
  const int l   = tid & 63;
  const int ql  = l & 31;
  const int hi  = l >> 5;
  const int qw0 = q0 + 32 * w;
  const int qa  = qw0 + ql;

  // staging roles (cover 64 rows x 16 float4 with 256 threads)
  const int sq  = l & 3;
  const int sm  = (l >> 2) & 3;
  const int sc2 = l >> 4;
  const int snb = 4 * w + 16 * sc2;  // n-chunk base (multiple of 4)

  __shared__ short Ksh[2][KVBLK * D_DIM];   // [n][d] bf16, FK-swizzled
  __shared__ short Vtsh[2][D_DIM * KVBLK];  // [d][n] bf16 (V^T), FV-swizzled
  __shared__ int anyPadSh;

  const unsigned char* PadB = Pad + (size_t)b * S_LEN;

  // ---- prologue: block-wide padding flag for this chunk's key range ----
  if (tid == 0) anyPadSh = 0;
  __syncthreads();
  {
    const int nk  = (t1 - t0) * KVBLK;      // <= 512
    const int idx = 2 * tid;
    if (idx < nk) {
      const unsigned char* pp = PadB + t0 * KVBLK + idx;
      const bool nz = pp[0] || ((idx + 1 < nk) ? pp[1] : (unsigned char)0);
      if (nz) anyPadSh = 1;                 // benign same-value race
    }
  }

  // ---- Q fragments (B-operand), pre-scaled by 1/8 ----
  s16x8 qf[4];
  {
    const float* qp = Qg + ((size_t)(b * S_LEN + qa)) * D_DIM + 8 * hi;
    #pragma unroll
    for (int dc = 0; dc < 4; ++dc)
      #pragma unroll
      for (int j = 0; j < 8; ++j)
        qf[dc][j] = (short)f2bfu(qp[16 * dc + j] * 0.125f);
  }

  f32x16 acc[2];
  #pragma unroll
  for (int dt = 0; dt < 2; ++dt)
    #pragma unroll
    for (int i = 0; i < 16; ++i) acc[dt][i] = 0.f;
  float mrow = -INFINITY;
  float lrow = 0.f;

  u32x2 kpb[4], vpb[4];   // bf16-packed prefetch (converted at load)

#define LOAD_K(T) do {                                                       \
    const int kv0_ = (T) * KVBLK;                                            \
    _Pragma("unroll")                                                        \
    for (int s_ = 0; s_ < 4; ++s_) {                                         \
      const size_t go_ =                                                     \
          ((size_t)(b * S_LEN + kv0_ + snb + sq)) * D_DIM + 16 * s_ + 4 * sm;\
      const float4 kx = *(const float4*)(Kg + go_);                          \
      kpb[s_][0] = pk2(kx.x, kx.y); kpb[s_][1] = pk2(kx.z, kx.w);            \
    }                                                                        \
  } while (0)

#define LOAD_V(T) do {                                                       \
    const int kv0_ = (T) * KVBLK;                                            \
    _Pragma("unroll")                                                        \
    for (int s_ = 0; s_ < 4; ++s_) {                                         \
      const size_t go_ =                                                     \
          ((size_t)(b * S_LEN + kv0_ + snb + sq)) * D_DIM + 16 * s_ + 4 * sm;\
      const float4 vx = *(const float4*)(Vg + go_);                          \
      vpb[s_][0] = pk2(vx.x, vx.y); vpb[s_][1] = pk2(vx.z, vx.w);            \
    }                                                                        \
  } while (0)

#define STAGE(BUF) do {                                                      \
    _Pragma("unroll")                                                        \
    for (int s_ = 0; s_ < 4; ++s_) {                                         \
      const int d0_ = 16 * s_ + 4 * sm; const int nk_ = snb + sq;            \
      *(u32x2*)((char*)&Ksh[BUF][0] + nk_ * 128 + ((2 * d0_) ^ FK(nk_))) =   \
          kpb[s_];                                                           \
      unsigned u0 = vpb[s_][0], u1 = vpb[s_][1];                             \
      unsigned x_ = (sq & 2) ? u0 : u1;                                      \
      unsigned y_ = __shfl_xor(x_, 2);                                       \
      unsigned A0 = (sq & 2) ? y_ : u0;                                      \
      unsigned A1 = (sq & 2) ? u1 : y_;                                      \
      unsigned z0 = __shfl_xor(A0, 1);                                       \
      unsigned z1 = __shfl_xor(A1, 1);                                       \
      unsigned o0, o1;                                                       \
      if (sq & 1) { o0 = (z0 >> 16) | (A0 & 0xFFFF0000u);                    \
                    o1 = (z1 >> 16) | (A1 & 0xFFFF0000u); }                  \
      else        { o0 = (A0 & 0xFFFFu) | (z0 << 16);                        \
                    o1 = (A1 & 0xFFFFu) | (z1 << 16); }                      \
      const int dv_ = d0_ + sq;                                              \
      u32x2 vv2; vv2[0] = o0; vv2[1] = o1;                                   \
      *(u32x2*)((char*)&Vtsh[BUF][0] + dv_ * 128 + ((2 * snb) ^ FV(dv_))) = vv2;\
    }                                                                        \
  } while (0)

  LOAD_K(t0);
  LOAD_V(t0);
  STAGE(0);
  __syncthreads();
  const bool hasPad = (anyPadSh != 0);
  int cb = 0;

  for (int t = t0; t < t1; ++t) {
    const int kv0 = t * KVBLK;
    const bool more = (t + 1 < t1);
    if (more) LOAD_K(t + 1);

    // ---- S^T = mfma(A=K, B=Q): col=lane&31=q, row=k ----
    f32x16 sv[2];
    __builtin_amdgcn_s_setprio(1);
    #pragma unroll
    for (int kt = 0; kt < 2; ++kt) {
      f32x16 a;
      #pragma unroll
      for (int i = 0; i < 16; ++i) a[i] = 0.f;
      #pragma unroll
      for (int dc = 0; dc < 4; ++dc) {
        const int nr = 32 * kt + ql;
        const s16x8 kf = *(const s16x8*)((char*)&Ksh[cb][0] + nr * 128 +
                                         ((32 * dc + 16 * hi) ^ FK(nr)));
        a = __builtin_amdgcn_mfma_f32_32x32x16_bf16(kf, qf[dc], a, 0, 0, 0);
      }
      sv[kt] = a;
    }
    __builtin_amdgcn_s_setprio(0);

    if (more) LOAD_V(t + 1);

    // ---- padding (rare path) ----
    if (hasPad) {
      #pragma unroll
      for (int kt = 0; kt < 2; ++kt)
        #pragma unroll
        for (int r1 = 0; r1 < 4; ++r1) {
          const unsigned pd =
              *(const unsigned*)(PadB + kv0 + 32 * kt + 8 * r1 + 4 * hi);
          #pragma unroll
          for (int r0 = 0; r0 < 4; ++r0)
            if ((pd >> (8 * r0)) & 0xFFu) sv[kt][4 * r1 + r0] = -1e30f;
        }
    }
    // ---- causal mask (diagonal band only): k = kv0+32kt+8r1+4hi+r0 ----
    #pragma unroll
    for (int kt = 0; kt < 2; ++kt) {
      const int kvt = kv0 + 32 * kt;
      if (kvt + 31 > qw0) {
        #pragma unroll
        for (int r1 = 0; r1 < 4; ++r1)
          #pragma unroll
          for (int r0 = 0; r0 < 4; ++r0)
            if (kvt + 8 * r1 + 4 * hi + r0 > qa) sv[kt][4 * r1 + r0] = -1e30f;
      }
    }

    // ---- in-register online softmax (e-domain, always rescale) ----
    float vm = sv[0][0];
    #pragma unroll
    for (int kt = 0; kt < 2; ++kt)
      #pragma unroll
      for (int i = 0; i < 16; ++i) vm = fmaxf(vm, sv[kt][i]);
    vm = fmaxf(vm, __shfl_xor(vm, 32));           // merge across hi halves
    const float mn   = fmaxf(mrow, vm);
    const float corr = __expf(mrow - mn);
    mrow = mn;
    lrow *= corr;
    #pragma unroll
    for (int dt = 0; dt < 2; ++dt)
      #pragma unroll
      for (int i = 0; i < 16; ++i) acc[dt][i] *= corr;

    float rs = 0.f;
    #pragma unroll
    for (int kt = 0; kt < 2; ++kt)
      #pragma unroll
      for (int i = 0; i < 16; ++i) {
        const float p = __expf(sv[kt][i] - mn);
        sv[kt][i] = p;
        rs += p;
      }
    lrow += rs;                                   // own half-sum only

    // ---- O^T += mfma(A=V^T, B=P) ----
    // P B-frag in C/D-native k-order: elem j <-> k = 4hi+(j&3)+8*(j>>2).
    // V^T A-frag reads the SAME element->k map (two 8B LDS reads).
    __builtin_amdgcn_s_setprio(1);
    #pragma unroll
    for (int sk = 0; sk < 4; ++sk) {
      const int kt = sk >> 1, rb = 8 * (sk & 1);
      union { unsigned u[4]; s16x8 v; } pb;
      pb.u[0] = pk2(sv[kt][rb + 0], sv[kt][rb + 1]);
      pb.u[1] = pk2(sv[kt][rb + 2], sv[kt][rb + 3]);
      pb.u[2] = pk2(sv[kt][rb + 4], sv[kt][rb + 5]);
      pb.u[3] = pk2(sv[kt][rb + 6], sv[kt][rb + 7]);
      #pragma unroll
      for (int dt = 0; dt < 2; ++dt) {
        const int dr = 32 * dt + ql;
        const char* vrow = (char*)&Vtsh[cb][0] + dr * 128;
        const s16x4 v0 = *(const s16x4*)(vrow + ((32 * sk + 8 * hi) ^ FV(dr)));
        const s16x4 v1 = *(const s16x4*)(vrow + ((32 * sk + 16 + 8 * hi) ^ FV(dr)));
        s16x8 vf;
        vf[0] = v0[0]; vf[1] = v0[1]; vf[2] = v0[2]; vf[3] = v0[3];
        vf[4] = v1[0]; vf[5] = v1[1]; vf[6] = v1[2]; vf[7] = v1[3];
        acc[dt] = __builtin_amdgcn_mfma_f32_32x32x16_bf16(vf, pb.v, acc[dt], 0, 0, 0);
      }
    }
    __builtin_amdgcn_s_setprio(0);

    if (more) STAGE(cb ^ 1);
    __syncthreads();
    cb ^= 1;
  }

  // ---- epilogue: merge l across hi halves; write partial slot ----
  const float lt = lrow + __shfl_xor(lrow, 32);

  float* slot = Ws + ((size_t)b * TOTC + u) * SLOT_F;
  const int row = 32 * w + ql;
  #pragma unroll
  for (int dt = 0; dt < 2; ++dt)
    #pragma unroll
    for (int r1 = 0; r1 < 4; ++r1) {
      f32x4 o;
      #pragma unroll
      for (int r0 = 0; r0 < 4; ++r0) o[r0] = acc[dt][4 * r1 + r0];
      *(f32x4*)(slot + row * 64 + 32 * dt + 8 * r1 + 4 * hi) = o;
    }
  if (hi == 0) {
    slot[QBLK * D_DIM + row]        = mrow;
    slot[QBLK * D_DIM + QBLK + row] = lt;
  }
}

__global__ __launch_bounds__(256, 8) void fattn_merge(
    const float* __restrict__ Ws, float* __restrict__ Og, int CL, int TOTC)
{
  const int blk = blockIdx.x;            // 512 = 128 qb * 4 quarters
  const int qbi = blk >> 2;
  const int qr  = blk & 3;
  const int Qb  = qbi & (NQB - 1);
  const int b   = qbi >> 5;
  const int tid = threadIdx.x;
  const int row = 32 * qr + (tid >> 3);  // q row within 128-block
  const int d0  = (tid & 7) * 8;         // 8 d-elems per thread

  const int ntt    = 2 * Qb + 2;
  const int nvalid = (ntt + CL - 1) / CL;
  int pre = 0;
  for (int q = 0; q < Qb; ++q) pre += (2 * q + 2 + CL - 1) / CL;

  const float* base = Ws + ((size_t)b * TOTC + pre) * SLOT_F;

  float mstar = -INFINITY;
  for (int ci = 0; ci < nvalid; ++ci)
    mstar = fmaxf(mstar, base[(size_t)ci * SLOT_F + QBLK * D_DIM + row]);

  float lsum = 0.f;
  float o[8];
  #pragma unroll
  for (int k = 0; k < 8; ++k) o[k] = 0.f;

  for (int ci = 0; ci < nvalid; ++ci) {
    const float* slot = base + (size_t)ci * SLOT_F;
    const float wgt = __expf(slot[QBLK * D_DIM + row] - mstar);
    lsum += wgt * slot[QBLK * D_DIM + QBLK + row];
    const float4 ov0 = *(const float4*)(slot + row * 64 + d0);
    const float4 ov1 = *(const float4*)(slot + row * 64 + d0 + 4);
    o[0] += wgt * ov0.x; o[1] += wgt * ov0.y;
    o[2] += wgt * ov0.z; o[3] += wgt * ov0.w;
    o[4] += wgt * ov1.x; o[5] += wgt * ov1.y;
    o[6] += wgt * ov1.z; o[7] += wgt * ov1.w;
  }

  const float inv = 1.0f / lsum;
  float* op = Og + ((size_t)(b * S_LEN + Qb * QBLK + row)) * D_DIM + d0;
  f32x4 o0, o1;
  #pragma unroll
  for (int k = 0; k < 4; ++k) { o0[k] = o[k] * inv; o1[k] = o[4 + k] * inv; }
  *(f32x4*)(op) = o0;
  *(f32x4*)(op + 4) = o1;
}

extern "C" void kernel_launch(void* const* d_in, const int* in_sizes, int n_in,
                              void* d_out, int out_size, void* d_ws, size_t ws_size,
                              hipStream_t stream) {
  const float* Q = (const float*)d_in[0];
  const float* K = (const float*)d_in[1];
  const float* V = (const float*)d_in[2];
  const unsigned char* P = (const unsigned char*)d_in[3];
  float* O  = (float*)d_out;
  float* Ws = (float*)d_ws;

  const size_t slot_bytes = (size_t)SLOT_F * 4;    // 33792 B
  // chunk length CL=4 if the slot pool fits, else 8 (known to fit)
  int CL = 4;
  int TOTC = 0;
  for (int q = 0; q < NQB; ++q) TOTC += (2 * q + 2 + CL - 1) / CL;   // 272
  if (ws_size < (size_t)NBATCH * TOTC * slot_bytes) {
    CL = 8;
    TOTC = 0;
    for (int q = 0; q < NQB; ++q) TOTC += (2 * q + 2 + CL - 1) / CL; // 144
  }

  dim3 grid(NBATCH * TOTC);
  dim3 block(256);
  hipLaunchKernelGGL(fattn_partial, grid, block, 0, stream, Q, K, V, P, Ws,
                     CL, TOTC);
  hipLaunchKernelGGL(fattn_merge, dim3(NBATCH * NQB * 4), dim3(256), 0, stream,
                     Ws, O, CL, TOTC);
}

// Round 12
// 60.090 us; speedup vs baseline: 1.5825x; 1.0048x over previous
//
#include <hip/hip_runtime.h>
#include <hip/hip_bf16.h>

// Flash attention fwd, causal + key-padding, B=4 S=4096 D=64, fp32 in/out.
// Round 12: round-11 green base (uniform CL-tile partition, heavy-first,
// bf16-at-load staging, dbuf LDS, anyPad prologue, always-rescale) with:
//  (a) TREE max-reduce (depth 33 -> ~6; linear chain was ~130 exposed cyc),
//  (b) 4-way parallel row-sum accumulators (depth 32 -> ~11),
//  (c) bf16 partial O slots (33.8 -> 17.4 KB/slot; m/l stay fp32) — halves
//      slot write + merge read traffic. Error budget +0.4% of |O| ~ +0.006.

#define S_LEN 4096
#define D_DIM 64
#define NBATCH 4
#define QBLK 128
#define KVBLK 64
#define NQB (S_LEN / QBLK)          // 32 q-blocks per batch
#define SLOT_B 17408                // 16K bf16 O + 1K fp32 m/l

typedef __attribute__((ext_vector_type(16))) float f32x16;
typedef __attribute__((ext_vector_type(4))) float f32x4;
typedef __attribute__((ext_vector_type(8))) short s16x8;
typedef __attribute__((ext_vector_type(4))) short s16x4;
typedef __attribute__((ext_vector_type(2))) unsigned int u32x2;

#define FK(n) ((((n) ^ ((n) >> 3)) & 7) << 4)                    // K swizzle
#define FV(d) (((((d) & 7) << 4)) ^ ((((d) >> 3) & 1) << 3))     // V^T swizzle

__device__ __forceinline__ unsigned short f2bfu(float f) {
  return __builtin_bit_cast(unsigned short, __float2bfloat16(f));
}
__device__ __forceinline__ unsigned pk2(float a, float b) {
  return (unsigned)f2bfu(a) | ((unsigned)f2bfu(b) << 16);
}
__device__ __forceinline__ float bf2f(short s) {
  return __builtin_bit_cast(float, ((unsigned)(unsigned short)s) << 16);
}

__global__ __launch_bounds__(256, 3) void fattn_partial(
    const float* __restrict__ Qg, const float* __restrict__ Kg,
    const float* __restrict__ Vg, const unsigned char* __restrict__ Pad,
    char* __restrict__ Ws, int CL, int TOTC)
{
  // Uniform partition: enumeration index u -> (Qb, ci); heavy-first.
  const int wid = blockIdx.x;
  const int b   = wid & 3;
  const int u   = TOTC - 1 - (wid >> 2);
  int Qb = 0, ci = 0;
  {
    int uu = u, q = 0;
    while (true) {
      const int nch = (2 * q + 2 + CL - 1) / CL;
      if (uu < nch) { ci = uu; break; }
      uu -= nch; ++q;
    }
    Qb = q;
  }
  const int q0  = Qb * QBLK;
  const int ntt = 2 * Qb + 2;
  const int t0  = ci * CL;
  const int t1  = (t0 + CL < ntt) ? (t0 + CL) : ntt;

  const int tid = threadIdx.x;
  const int w   = tid >> 6;          // wave 0..3 -> q rows [q0+32w, q0+32w+32)
  const int l   = tid & 63;
  const int ql  = l & 31;
  const int hi  = l >> 5;
  const int qw0 = q0 + 32 * w;
  const int qa  = qw0 + ql;

  // staging roles (cover 64 rows x 16 float4 with 256 threads)
  const int sq  = l & 3;
  const int sm  = (l >> 2) & 3;
  const int sc2 = l >> 4;
  const int snb = 4 * w + 16 * sc2;  // n-chunk base (multiple of 4)

  __shared__ short Ksh[2][KVBLK * D_DIM];   // [n][d] bf16, FK-swizzled
  __shared__ short Vtsh[2][D_DIM * KVBLK];  // [d][n] bf16 (V^T), FV-swizzled
  __shared__ int anyPadSh;

  const unsigned char* PadB = Pad + (size_t)b * S_LEN;

  // ---- prologue: block-wide padding flag for this chunk's key range ----
  if (tid == 0) anyPadSh = 0;
  __syncthreads();
  {
    const int nk  = (t1 - t0) * KVBLK;      // <= 512
    const int idx = 2 * tid;
    if (idx < nk) {
      const unsigned char* pp = PadB + t0 * KVBLK + idx;
      const bool nz = pp[0] || ((idx + 1 < nk) ? pp[1] : (unsigned char)0);
      if (nz) anyPadSh = 1;                 // benign same-value race
    }
  }

  // ---- Q fragments (B-operand), pre-scaled by 1/8 ----
  s16x8 qf[4];
  {
    const float* qp = Qg + ((size_t)(b * S_LEN + qa)) * D_DIM + 8 * hi;
    #pragma unroll
    for (int dc = 0; dc < 4; ++dc)
      #pragma unroll
      for (int j = 0; j < 8; ++j)
        qf[dc][j] = (short)f2bfu(qp[16 * dc + j] * 0.125f);
  }

  f32x16 acc[2];
  #pragma unroll
  for (int dt = 0; dt < 2; ++dt)
    #pragma unroll
    for (int i = 0; i < 16; ++i) acc[dt][i] = 0.f;
  float mrow = -INFINITY;
  float lrow = 0.f;

  u32x2 kpb[4], vpb[4];   // bf16-packed prefetch (converted at load)

#define LOAD_K(T) do {                                                       \
    const int kv0_ = (T) * KVBLK;                                            \
    _Pragma("unroll")                                                        \
    for (int s_ = 0; s_ < 4; ++s_) {                                         \
      const size_t go_ =                                                     \
          ((size_t)(b * S_LEN + kv0_ + snb + sq)) * D_DIM + 16 * s_ + 4 * sm;\
      const float4 kx = *(const float4*)(Kg + go_);                          \
      kpb[s_][0] = pk2(kx.x, kx.y); kpb[s_][1] = pk2(kx.z, kx.w);            \
    }                                                                        \
  } while (0)

#define LOAD_V(T) do {                                                       \
    const int kv0_ = (T) * KVBLK;                                            \
    _Pragma("unroll")                                                        \
    for (int s_ = 0; s_ < 4; ++s_) {                                         \
      const size_t go_ =                                                     \
          ((size_t)(b * S_LEN + kv0_ + snb + sq)) * D_DIM + 16 * s_ + 4 * sm;\
      const float4 vx = *(const float4*)(Vg + go_);                          \
      vpb[s_][0] = pk2(vx.x, vx.y); vpb[s_][1] = pk2(vx.z, vx.w);            \
    }                                                                        \
  } while (0)

#define STAGE(BUF) do {                                                      \
    _Pragma("unroll")                                                        \
    for (int s_ = 0; s_ < 4; ++s_) {                                         \
      const int d0_ = 16 * s_ + 4 * sm; const int nk_ = snb + sq;            \
      *(u32x2*)((char*)&Ksh[BUF][0] + nk_ * 128 + ((2 * d0_) ^ FK(nk_))) =   \
          kpb[s_];                                                           \
      unsigned u0 = vpb[s_][0], u1 = vpb[s_][1];                             \
      unsigned x_ = (sq & 2) ? u0 : u1;                                      \
      unsigned y_ = __shfl_xor(x_, 2);                                       \
      unsigned A0 = (sq & 2) ? y_ : u0;                                      \
      unsigned A1 = (sq & 2) ? u1 : y_;                                      \
      unsigned z0 = __shfl_xor(A0, 1);                                       \
      unsigned z1 = __shfl_xor(A1, 1);                                       \
      unsigned o0, o1;                                                       \
      if (sq & 1) { o0 = (z0 >> 16) | (A0 & 0xFFFF0000u);                    \
                    o1 = (z1 >> 16) | (A1 & 0xFFFF0000u); }                  \
      else        { o0 = (A0 & 0xFFFFu) | (z0 << 16);                        \
                    o1 = (A1 & 0xFFFFu) | (z1 << 16); }                      \
      const int dv_ = d0_ + sq;                                              \
      u32x2 vv2; vv2[0] = o0; vv2[1] = o1;                                   \
      *(u32x2*)((char*)&Vtsh[BUF][0] + dv_ * 128 + ((2 * snb) ^ FV(dv_))) = vv2;\
    }                                                                        \
  } while (0)

  LOAD_K(t0);
  LOAD_V(t0);
  STAGE(0);
  __syncthreads();
  const bool hasPad = (anyPadSh != 0);
  int cb = 0;

  for (int t = t0; t < t1; ++t) {
    const int kv0 = t * KVBLK;
    const bool more = (t + 1 < t1);
    if (more) LOAD_K(t + 1);

    // ---- S^T = mfma(A=K, B=Q): col=lane&31=q, row=k ----
    f32x16 sv[2];
    __builtin_amdgcn_s_setprio(1);
    #pragma unroll
    for (int kt = 0; kt < 2; ++kt) {
      f32x16 a;
      #pragma unroll
      for (int i = 0; i < 16; ++i) a[i] = 0.f;
      #pragma unroll
      for (int dc = 0; dc < 4; ++dc) {
        const int nr = 32 * kt + ql;
        const s16x8 kf = *(const s16x8*)((char*)&Ksh[cb][0] + nr * 128 +
                                         ((32 * dc + 16 * hi) ^ FK(nr)));
        a = __builtin_amdgcn_mfma_f32_32x32x16_bf16(kf, qf[dc], a, 0, 0, 0);
      }
      sv[kt] = a;
    }
    __builtin_amdgcn_s_setprio(0);

    if (more) LOAD_V(t + 1);

    // ---- padding (rare path) ----
    if (hasPad) {
      #pragma unroll
      for (int kt = 0; kt < 2; ++kt)
        #pragma unroll
        for (int r1 = 0; r1 < 4; ++r1) {
          const unsigned pd =
              *(const unsigned*)(PadB + kv0 + 32 * kt + 8 * r1 + 4 * hi);
          #pragma unroll
          for (int r0 = 0; r0 < 4; ++r0)
            if ((pd >> (8 * r0)) & 0xFFu) sv[kt][4 * r1 + r0] = -1e30f;
        }
    }
    // ---- causal mask (diagonal band only): k = kv0+32kt+8r1+4hi+r0 ----
    #pragma unroll
    for (int kt = 0; kt < 2; ++kt) {
      const int kvt = kv0 + 32 * kt;
      if (kvt + 31 > qw0) {
        #pragma unroll
        for (int r1 = 0; r1 < 4; ++r1)
          #pragma unroll
          for (int r0 = 0; r0 < 4; ++r0)
            if (kvt + 8 * r1 + 4 * hi + r0 > qa) sv[kt][4 * r1 + r0] = -1e30f;
      }
    }

    // ---- in-register online softmax: TREE max, 4-way sum ----
    f32x16 mx;
    #pragma unroll
    for (int i = 0; i < 16; ++i) mx[i] = fmaxf(sv[0][i], sv[1][i]);
    f32x4 m4;
    #pragma unroll
    for (int i = 0; i < 4; ++i)
      m4[i] = fmaxf(fmaxf(mx[i], mx[i + 4]), fmaxf(mx[i + 8], mx[i + 12]));
    float vm = fmaxf(fmaxf(m4[0], m4[1]), fmaxf(m4[2], m4[3]));
    vm = fmaxf(vm, __shfl_xor(vm, 32));           // merge across hi halves
    const float mn   = fmaxf(mrow, vm);
    const float corr = __expf(mrow - mn);
    mrow = mn;
    lrow *= corr;
    #pragma unroll
    for (int dt = 0; dt < 2; ++dt)
      #pragma unroll
      for (int i = 0; i < 16; ++i) acc[dt][i] *= corr;

    float rs0 = 0.f, rs1 = 0.f, rs2 = 0.f, rs3 = 0.f;
    #pragma unroll
    for (int kt = 0; kt < 2; ++kt)
      #pragma unroll
      for (int i4 = 0; i4 < 16; i4 += 4) {
        const float p0 = __expf(sv[kt][i4 + 0] - mn);
        const float p1 = __expf(sv[kt][i4 + 1] - mn);
        const float p2 = __expf(sv[kt][i4 + 2] - mn);
        const float p3 = __expf(sv[kt][i4 + 3] - mn);
        sv[kt][i4 + 0] = p0; sv[kt][i4 + 1] = p1;
        sv[kt][i4 + 2] = p2; sv[kt][i4 + 3] = p3;
        rs0 += p0; rs1 += p1; rs2 += p2; rs3 += p3;
      }
    lrow += (rs0 + rs1) + (rs2 + rs3);            // own half-sum only

    // ---- O^T += mfma(A=V^T, B=P) ----
    // P B-frag in C/D-native k-order: elem j <-> k = 4hi+(j&3)+8*(j>>2).
    // V^T A-frag reads the SAME element->k map (two 8B LDS reads).
    __builtin_amdgcn_s_setprio(1);
    #pragma unroll
    for (int sk = 0; sk < 4; ++sk) {
      const int kt = sk >> 1, rb = 8 * (sk & 1);
      union { unsigned u[4]; s16x8 v; } pb;
      pb.u[0] = pk2(sv[kt][rb + 0], sv[kt][rb + 1]);
      pb.u[1] = pk2(sv[kt][rb + 2], sv[kt][rb + 3]);
      pb.u[2] = pk2(sv[kt][rb + 4], sv[kt][rb + 5]);
      pb.u[3] = pk2(sv[kt][rb + 6], sv[kt][rb + 7]);
      #pragma unroll
      for (int dt = 0; dt < 2; ++dt) {
        const int dr = 32 * dt + ql;
        const char* vrow = (char*)&Vtsh[cb][0] + dr * 128;
        const s16x4 v0 = *(const s16x4*)(vrow + ((32 * sk + 8 * hi) ^ FV(dr)));
        const s16x4 v1 = *(const s16x4*)(vrow + ((32 * sk + 16 + 8 * hi) ^ FV(dr)));
        s16x8 vf;
        vf[0] = v0[0]; vf[1] = v0[1]; vf[2] = v0[2]; vf[3] = v0[3];
        vf[4] = v1[0]; vf[5] = v1[1]; vf[6] = v1[2]; vf[7] = v1[3];
        acc[dt] = __builtin_amdgcn_mfma_f32_32x32x16_bf16(vf, pb.v, acc[dt], 0, 0, 0);
      }
    }
    __builtin_amdgcn_s_setprio(0);

    if (more) STAGE(cb ^ 1);
    __syncthreads();
    cb ^= 1;
  }

  // ---- epilogue: merge l across hi halves; write bf16 partial slot ----
  const float lt = lrow + __shfl_xor(lrow, 32);

  char* slot = Ws + ((size_t)b * TOTC + u) * SLOT_B;
  const int row = 32 * w + ql;
  #pragma unroll
  for (int dt = 0; dt < 2; ++dt)
    #pragma unroll
    for (int r1 = 0; r1 < 4; ++r1) {
      u32x2 p;
      p[0] = pk2(acc[dt][4 * r1 + 0], acc[dt][4 * r1 + 1]);
      p[1] = pk2(acc[dt][4 * r1 + 2], acc[dt][4 * r1 + 3]);
      *(u32x2*)(slot + row * 128 + (32 * dt + 8 * r1 + 4 * hi) * 2) = p;
    }
  if (hi == 0) {
    ((float*)(slot + 16384))[row]       = mrow;
    ((float*)(slot + 16384 + 512))[row] = lt;
  }
}

__global__ __launch_bounds__(256, 8) void fattn_merge(
    const char* __restrict__ Ws, float* __restrict__ Og, int CL, int TOTC)
{
  const int blk = blockIdx.x;            // 512 = 128 qb * 4 quarters
  const int qbi = blk >> 2;
  const int qr  = blk & 3;
  const int Qb  = qbi & (NQB - 1);
  const int b   = qbi >> 5;
  const int tid = threadIdx.x;
  const int row = 32 * qr + (tid >> 3);  // q row within 128-block
  const int d0  = (tid & 7) * 8;         // 8 d-elems per thread

  const int ntt    = 2 * Qb + 2;
  const int nvalid = (ntt + CL - 1) / CL;
  int pre = 0;
  for (int q = 0; q < Qb; ++q) pre += (2 * q + 2 + CL - 1) / CL;

  const char* base = Ws + ((size_t)b * TOTC + pre) * SLOT_B;

  float mstar = -INFINITY;
  for (int ci = 0; ci < nvalid; ++ci)
    mstar = fmaxf(mstar, ((const float*)(base + (size_t)ci * SLOT_B + 16384))[row]);

  float lsum = 0.f;
  float o[8];
  #pragma unroll
  for (int k = 0; k < 8; ++k) o[k] = 0.f;

  for (int ci = 0; ci < nvalid; ++ci) {
    const char* slot = base + (size_t)ci * SLOT_B;
    const float wgt = __expf(((const float*)(slot + 16384))[row] - mstar);
    lsum += wgt * ((const float*)(slot + 16384 + 512))[row];
    const s16x8 ov = *(const s16x8*)(slot + row * 128 + d0 * 2);
    #pragma unroll
    for (int k = 0; k < 8; ++k) o[k] += wgt * bf2f(ov[k]);
  }

  const float inv = 1.0f / lsum;
  float* op = Og + ((size_t)(b * S_LEN + Qb * QBLK + row)) * D_DIM + d0;
  f32x4 o0, o1;
  #pragma unroll
  for (int k = 0; k < 4; ++k) { o0[k] = o[k] * inv; o1[k] = o[4 + k] * inv; }
  *(f32x4*)(op) = o0;
  *(f32x4*)(op + 4) = o1;
}

extern "C" void kernel_launch(void* const* d_in, const int* in_sizes, int n_in,
                              void* d_out, int out_size, void* d_ws, size_t ws_size,
                              hipStream_t stream) {
  const float* Q = (const float*)d_in[0];
  const float* K = (const float*)d_in[1];
  const float* V = (const float*)d_in[2];
  const unsigned char* P = (const unsigned char*)d_in[3];
  float* O  = (float*)d_out;
  char*  Ws = (char*)d_ws;

  // chunk length CL=4 if the slot pool fits, else 8
  int CL = 4;
  int TOTC = 0;
  for (int q = 0; q < NQB; ++q) TOTC += (2 * q + 2 + CL - 1) / CL;   // 272
  if (ws_size < (size_t)NBATCH * TOTC * SLOT_B) {
    CL = 8;
    TOTC = 0;
    for (int q = 0; q < NQB; ++q) TOTC += (2 * q + 2 + CL - 1) / CL; // 144
  }

  dim3 grid(NBATCH * TOTC);
  dim3 block(256);
  hipLaunchKernelGGL(fattn_partial, grid, block, 0, stream, Q, K, V, P, Ws,
                     CL, TOTC);
  hipLaunchKernelGGL(fattn_merge, dim3(NBATCH * NQB * 4), dim3(256), 0, stream,
                     Ws, O, CL, TOTC);
}